// Round 3
// baseline (2350.089 us; speedup 1.0000x reference)
//
#include <hip/hip_runtime.h>

#define E_EDGES 320000
#define N_NODES 10000
#define F_DIM   128
#define C_DIM   384      // 3*F
#define NRBF_K  20
#define TILE    16       // edges per tile inside a node
#define TP      20       // padded stride for [.][e] tiles (16B-aligned rows)
#define PI_F    3.14159265358979323846f

// ws layout (bytes): [0] sumsq (16B slot) | [16] cnt[10000] | [40016] row[10001]
//                    | [80020] cur[10000] | [120020] order[320000]   total ~1.34 MB
#define WS_CNT_OFF   16
#define WS_ROW_OFF   40016
#define WS_CUR_OFF   80020
#define WS_ORD_OFF   120020

// ---------------------------------------------------------------- sum(r^2) over all E*3
__global__ void sumsq_kernel(const float* __restrict__ r, float* __restrict__ out) {
    __shared__ float red[4];
    int tid = blockIdx.x * blockDim.x + threadIdx.x;
    int stride = gridDim.x * blockDim.x;
    float acc = 0.f;
    for (int i = tid; i < E_EDGES * 3; i += stride) {
        float x = r[i];
        acc += x * x;
    }
    #pragma unroll
    for (int off = 32; off > 0; off >>= 1)
        acc += __shfl_down(acc, off, 64);
    int lane = threadIdx.x & 63;
    int wave = threadIdx.x >> 6;
    if (lane == 0) red[wave] = acc;
    __syncthreads();
    if (threadIdx.x == 0) atomicAdd(out, red[0] + red[1] + red[2] + red[3]);
}

// ---------------------------------------------------------------- CSR build
__global__ void hist_kernel(const int* __restrict__ idx_i, int* __restrict__ cnt) {
    int e = blockIdx.x * blockDim.x + threadIdx.x;
    if (e < E_EDGES) atomicAdd(&cnt[idx_i[e]], 1);
}

__global__ __launch_bounds__(1024) void scan_kernel(const int* __restrict__ cnt,
                                                    int* __restrict__ row,
                                                    int* __restrict__ cur) {
    __shared__ int sdata[1024];
    __shared__ int carry;
    const int tid = threadIdx.x;
    if (tid == 0) carry = 0;
    __syncthreads();
    for (int base = 0; base < N_NODES; base += 1024) {
        int x = (base + tid < N_NODES) ? cnt[base + tid] : 0;
        sdata[tid] = x;
        __syncthreads();
        #pragma unroll
        for (int off = 1; off < 1024; off <<= 1) {
            int y = (tid >= off) ? sdata[tid - off] : 0;
            __syncthreads();
            sdata[tid] += y;
            __syncthreads();
        }
        int excl = carry + sdata[tid] - x;   // exclusive prefix
        if (base + tid < N_NODES) { row[base + tid] = excl; cur[base + tid] = excl; }
        __syncthreads();                      // everyone read carry before update
        if (tid == 0) carry += sdata[1023];
        __syncthreads();
    }
    if (tid == 0) row[N_NODES] = E_EDGES;
}

__global__ void fill_kernel(const int* __restrict__ idx_i,
                            int* __restrict__ cur, int* __restrict__ order) {
    int e = blockIdx.x * blockDim.x + threadIdx.x;
    if (e < E_EDGES) {
        int pos = atomicAdd(&cur[idx_i[e]], 1);
        order[pos] = e;
    }
}

// ---------------------------------------------------------------- node-centric gather
__global__ __launch_bounds__(384) void gather_kernel(
    const float* __restrict__ s,      // E x 128
    const float* __restrict__ r,      // E x 3
    const float* __restrict__ v,      // E x 3 x 128
    const float* __restrict__ W_phi,  // 128 x 384
    const float* __restrict__ b_phi,  // 384
    const float* __restrict__ W_w,    // 20 x 384
    const float* __restrict__ b_w,    // 384
    const float* __restrict__ sumsq,  // ws scalar
    const int*   __restrict__ row,    // N+1
    const int*   __restrict__ order,  // E (edge ids grouped by node)
    float* __restrict__ out)          // [out_v N*3*128][out_s N*128]
{
    __shared__ float s_tile[F_DIM][TP];         // [k][slot]
    __shared__ float rbf_sh[NRBF_K][TP];        // [nrbf][slot]
    __shared__ float orn_sh[TILE][3];
    __shared__ float split_sh[C_DIM][TILE + 1]; // [j][slot]
    __shared__ int   eid_sh[TILE];

    const int tid = threadIdx.x;                // 0..383 == column j
    const int j   = tid;
    const int n   = blockIdx.x;
    const int beg = row[n];
    const int cnt = row[n + 1] - beg;
    const float inv_gn = rsqrtf(*sumsq);
    const float bp = b_phi[j];
    const float bw = b_w[j];
    const int f = tid & 127;
    const int d = tid >> 7;                     // wave-uniform

    float acc_v = 0.f, acc_s = 0.f;

    for (int base = 0; base < cnt; base += TILE) {
        const int m = min(TILE, cnt - base);    // valid slots, uniform per block

        // ---- stage: s tile, rbf, org_rn, edge ids (slots >= m clamp to m-1) ----
        for (int q = tid; q < TILE * F_DIM; q += 384) {
            int sl = q >> 7, k = q & 127;
            int eid = order[beg + base + min(sl, m - 1)];
            s_tile[k][sl] = s[(size_t)eid * F_DIM + k];
        }
        if (tid < TILE * NRBF_K) {              // 320 threads: one (slot, nrbf)
            int sl = tid / NRBF_K, nb = tid % NRBF_K;
            int eid = order[beg + base + min(sl, m - 1)];
            float r0 = r[eid * 3 + 0];
            float r1 = r[eid * 3 + 1];
            float r2 = r[eid * 3 + 2];
            float rn = sqrtf(r0 * r0 + r1 * r1 + r2 * r2);
            float arg  = (float)(nb + 1) * (PI_F / 5.0f) * rn;
            float tval = sinf(arg) / rn;
            rbf_sh[nb][sl] = (tval <= 5.0f) ? 0.5f * (cosf(PI_F * tval / 5.0f) + 1.0f)
                                            : 0.0f;
        }
        if (tid >= 320 && tid < 320 + TILE * 3) {
            int q = tid - 320; int sl = q / 3, dd = q % 3;
            int eid = order[beg + base + min(sl, m - 1)];
            orn_sh[sl][dd] = r[eid * 3 + dd] * inv_gn;
        }
        if (tid >= 368) {                       // 16 threads: edge ids for v loads
            int sl = tid - 368;
            eid_sh[sl] = order[beg + base + min(sl, m - 1)];
        }
        __syncthreads();

        // ---- compute: phi = s@W_phi + b_phi ; w = rbf@W_w + b_w ; split = w*phi ----
        float accp[TILE], accw[TILE];
        #pragma unroll
        for (int sl = 0; sl < TILE; sl++) { accp[sl] = bp; accw[sl] = bw; }

        for (int k = 0; k < F_DIM; k++) {
            float wv = W_phi[k * C_DIM + j];
            const float4* s4 = (const float4*)(&s_tile[k][0]);
            float sv[TILE];
            *(float4*)&sv[0]  = s4[0];
            *(float4*)&sv[4]  = s4[1];
            *(float4*)&sv[8]  = s4[2];
            *(float4*)&sv[12] = s4[3];
            #pragma unroll
            for (int sl = 0; sl < TILE; sl++) accp[sl] += wv * sv[sl];
        }
        #pragma unroll
        for (int nb = 0; nb < NRBF_K; nb++) {
            float wv = W_w[nb * C_DIM + j];
            const float4* r4 = (const float4*)(&rbf_sh[nb][0]);
            float rv[TILE];
            *(float4*)&rv[0]  = r4[0];
            *(float4*)&rv[4]  = r4[1];
            *(float4*)&rv[8]  = r4[2];
            *(float4*)&rv[12] = r4[3];
            #pragma unroll
            for (int sl = 0; sl < TILE; sl++) accw[sl] += wv * rv[sl];
        }
        #pragma unroll
        for (int sl = 0; sl < TILE; sl++) split_sh[j][sl] = accp[sl] * accw[sl];
        __syncthreads();

        // ---- accumulate into registers (no atomics) ----
        for (int sl = 0; sl < m; sl++) {
            int eid = eid_sh[sl];
            float vv  = v[(size_t)eid * C_DIM + tid];
            acc_v += split_sh[f][sl] * vv + split_sh[256 + f][sl] * orn_sh[sl][d];
            if (d == 0) acc_s += split_sh[128 + f][sl];
        }
        __syncthreads();
    }

    // ---- single coalesced store per node ----
    out[(size_t)n * C_DIM + tid] = acc_v;                       // out_v (N,3,F)
    if (d == 0) out[(size_t)N_NODES * C_DIM + n * F_DIM + f] = acc_s;  // out_s (N,F)
}

extern "C" void kernel_launch(void* const* d_in, const int* in_sizes, int n_in,
                              void* d_out, int out_size, void* d_ws, size_t ws_size,
                              hipStream_t stream) {
    const float* s     = (const float*)d_in[0];
    const float* r     = (const float*)d_in[1];
    const float* v     = (const float*)d_in[2];
    const int*   idx_i = (const int*)d_in[3];
    const float* W_phi = (const float*)d_in[4];
    const float* b_phi = (const float*)d_in[5];
    const float* W_w   = (const float*)d_in[6];
    const float* b_w   = (const float*)d_in[7];

    float* out   = (float*)d_out;
    char*  ws    = (char*)d_ws;
    float* sumsq = (float*)ws;
    int*   cnt   = (int*)(ws + WS_CNT_OFF);
    int*   rowp  = (int*)(ws + WS_ROW_OFF);
    int*   cur   = (int*)(ws + WS_CUR_OFF);
    int*   order = (int*)(ws + WS_ORD_OFF);

    // zero sumsq + histogram counters (contiguous prefix of ws)
    hipMemsetAsync(d_ws, 0, WS_CNT_OFF + N_NODES * sizeof(int), stream);

    sumsq_kernel<<<512, 256, 0, stream>>>(r, sumsq);
    hist_kernel<<<(E_EDGES + 255) / 256, 256, 0, stream>>>(idx_i, cnt);
    scan_kernel<<<1, 1024, 0, stream>>>(cnt, rowp, cur);
    fill_kernel<<<(E_EDGES + 255) / 256, 256, 0, stream>>>(idx_i, cur, order);
    gather_kernel<<<N_NODES, 384, 0, stream>>>(s, r, v, W_phi, b_phi, W_w, b_w,
                                               sumsq, rowp, order, out);
}